// Round 1
// baseline (247.575 us; speedup 1.0000x reference)
//
#include <hip/hip_runtime.h>
#include <math.h>

// x: [B=32, T=2048, H=512] fp32, alpha: [H,3] -> out [B,T,H] fp32.
// Per-feature softmax blend of 3 sliding-window z-scores (w=5,10,20),
// replicate-padded at front, unbiased std, sd clamped at 1e-4.
//
// R4 design: one thread per SINGLE feature column (512 threads/block).
// 20-step history in a per-thread-private LDS ring (ring[slot][tid], no
// barriers). Ring = 20*512*4 = 40960 B -> 4 blocks/CU (160 KiB) but now
// 8 waves/block => 32 waves/CU (100% occupancy) vs R3's 16.
// __launch_bounds__(512,8) forces VGPR<=64 so VGPRs don't cap occupancy.
// Main loop: groups of 4 t-steps with explicit next-group prefetch
// (double-buffered, branchless via row clamp) -> up to 8 loads in flight/wave.
// Output via nontemporal stores (never re-read; keep L2/L3 for x halo).

#define BB 32
#define TT 2048
#define HH 512
#define CHUNK 64    // grid = (2048/64=32) x 32 = 1024 blocks, 8192 waves = 32/CU

static __device__ __forceinline__ int imin(int a, int b) { return a < b ? a : b; }

__global__ __launch_bounds__(512, 8) void fan_kernel(const float* __restrict__ x,
                                                     const float* __restrict__ alpha,
                                                     float* __restrict__ out) {
    __shared__ float ring[20][HH];   // 40960 B

    const int tid = threadIdx.x;     // feature index h
    const int t0  = blockIdx.x * CHUNK;
    const int b   = blockIdx.y;

    constexpr int   W[3]       = {5, 10, 20};
    constexpr float INV_W[3]   = {0.2f, 0.1f, 0.05f};
    constexpr float INV_WM1[3] = {0.25f, 1.0f/9.0f, 1.0f/19.0f};

    // per-feature softmax over the 3 windows (1 channel per thread)
    float aw[3];
    {
        const float* a = alpha + 3 * tid;
        float f0 = a[0], f1 = a[1], f2 = a[2];
        float mx = fmaxf(f0, fmaxf(f1, f2));
        float e0 = __expf(f0 - mx);
        float e1 = __expf(f1 - mx);
        float e2 = __expf(f2 - mx);
        float inv = 1.0f / (e0 + e1 + e2);
        aw[0] = e0 * inv; aw[1] = e1 * inv; aw[2] = e2 * inv;
    }

    const float* __restrict__ px = x   + (size_t)b * TT * HH + tid;
    float*       __restrict__ po = out + (size_t)b * TT * HH + tid;

    float S[3]  = {0.f, 0.f, 0.f};
    float S2[3] = {0.f, 0.f, 0.f};
    int tstart;

    if (t0 == 0) {
        // ---- pass 1: prescan rows [0,20), fill ring, prefix checkpoints at 5,10,15,20
        float P = 0.f, Q = 0.f;
        float CP[4], CQ[4];
        #pragma unroll
        for (int t = 0; t < 20; ++t) {
            float v = px[(size_t)t * HH];
            ring[t][tid] = v;
            P += v; Q += v * v;
            if (t == 4 || t == 9 || t == 14 || t == 19) {
                const int ci = (t + 1) / 5 - 1;
                CP[ci] = P; CQ[ci] = Q;
            }
        }
        // replicate stats: windows [0,w-1] -> checkpoints 5,10,20 (idx 0,1,3)
        float rmu[3], rrsd[3];
        constexpr int CMAP[3] = {0, 1, 3};
        #pragma unroll
        for (int i = 0; i < 3; ++i) {
            float s = CP[CMAP[i]], s2 = CQ[CMAP[i]];
            float mu  = s * INV_W[i];
            float var = fmaxf((s2 - s * mu) * INV_WM1[i], 0.f);
            rmu[i]  = mu;
            rrsd[i] = fminf(__builtin_amdgcn_rsqf(var), 1e4f);
        }
        // ---- pass 2: outputs [0,20) from ring (LDS-resident), running clipped sums
        #pragma unroll
        for (int t = 0; t < 20; ++t) {
            float v = ring[t][tid];
            float acc = 0.f;
            #pragma unroll
            for (int i = 0; i < 3; ++i) {
                if (t >= W[i]) {
                    float o = ring[t - W[i]][tid];
                    S[i]  += v - o;
                    S2[i] += v * v - o * o;
                } else {
                    S[i]  += v;
                    S2[i] += v * v;
                }
                float mu, rs;
                if (t >= W[i] - 1) {
                    mu = S[i] * INV_W[i];
                    float var = fmaxf((S2[i] - S[i] * mu) * INV_WM1[i], 0.f);
                    rs = fminf(__builtin_amdgcn_rsqf(var), 1e4f);
                } else {
                    mu = rmu[i]; rs = rrsd[i];
                }
                acc = fmaf((v - mu) * rs, aw[i], acc);
            }
            __builtin_nontemporal_store(acc, &po[(size_t)t * HH]);
        }
        // entry sums for t=20: S_w = P20 - P(20-w)
        S[0] = CP[3] - CP[2];  S2[0] = CQ[3] - CQ[2];
        S[1] = CP[3] - CP[1];  S2[1] = CQ[3] - CQ[1];
        S[2] = CP[3];          S2[2] = CQ[3];
        tstart = 20;
    } else {
        // ---- interior warm-up: rows [t0-20, t0-1] -> ring + clipped sums
        int s = t0 % 20;               // slot of row t0-20 ( == (t0-20)%20 )
        #pragma unroll
        for (int k = 20; k >= 1; --k) {
            const int t = t0 - k;
            float v = px[(size_t)t * HH];
            ring[s][tid] = v;
            s = (s == 19) ? 0 : s + 1;
            #pragma unroll
            for (int i = 0; i < 3; ++i)
                if (k <= W[i]) { S[i] += v; S2[i] += v * v; }
        }
        tstart = t0;
    }

    // ---- main loop: groups of 4, explicit next-group prefetch; slots mod 20
    int m0  = tstart % 20;          // slot of x[t-20] == slot to write x[t]
    int m5  = m0 + 15; if (m5  >= 20) m5  -= 20;   // slot of x[t-5]
    int m10 = m0 + 10; if (m10 >= 20) m10 -= 20;   // slot of x[t-10]

    const int tend = t0 + CHUNK;

    float Vb[4];
    #pragma unroll
    for (int g = 0; g < 4; ++g) Vb[g] = px[(size_t)(tstart + g) * HH];

    for (int t = tstart; t < tend; t += 4) {
        // prefetch next group (branchless: clamp keeps rows in-bounds; extra
        // rows loaded past tend are valid data, just unused)
        const int tn = imin(t + 4, TT - 4);
        float Vn[4];
        #pragma unroll
        for (int g = 0; g < 4; ++g) Vn[g] = px[(size_t)(tn + g) * HH];

        #pragma unroll
        for (int g = 0; g < 4; ++g) {
            float o20 = ring[m0][tid];      // read delay-20 BEFORE overwrite
            float o5  = ring[m5][tid];
            float o10 = ring[m10][tid];
            ring[m0][tid] = Vb[g];

            const float v = Vb[g];
            float od[3] = {o5, o10, o20};
            float acc = 0.f;
            #pragma unroll
            for (int i = 0; i < 3; ++i) {
                float oo = od[i];
                S[i]  += v - oo;
                S2[i] += v * v - oo * oo;
                float mu  = S[i] * INV_W[i];
                float var = fmaxf((S2[i] - S[i] * mu) * INV_WM1[i], 0.f);
                float rs  = fminf(__builtin_amdgcn_rsqf(var), 1e4f);
                acc = fmaf((v - mu) * rs, aw[i], acc);
            }
            __builtin_nontemporal_store(acc, &po[(size_t)(t + g) * HH]);

            m0  = (m0  == 19) ? 0 : m0  + 1;
            m5  = (m5  == 19) ? 0 : m5  + 1;
            m10 = (m10 == 19) ? 0 : m10 + 1;
        }

        #pragma unroll
        for (int g = 0; g < 4; ++g) Vb[g] = Vn[g];
    }
}

extern "C" void kernel_launch(void* const* d_in, const int* in_sizes, int n_in,
                              void* d_out, int out_size, void* d_ws, size_t ws_size,
                              hipStream_t stream) {
    const float* x     = (const float*)d_in[0];
    const float* alpha = (const float*)d_in[1];
    float*       out   = (float*)d_out;

    dim3 grid(TT / CHUNK, BB);   // 32 x 32 = 1024 blocks
    dim3 block(512);             // one thread per feature column of H
    fan_kernel<<<grid, block, 0, stream>>>(x, alpha, out);
}

// Round 2
// 245.934 us; speedup vs baseline: 1.0067x; 1.0067x over previous
//
#include <hip/hip_runtime.h>
#include <math.h>

// x: [B=32, T=2048, H=512] fp32, alpha: [H,3] -> out [B,T,H] fp32.
// Per-feature softmax blend of 3 sliding-window z-scores (w=5,10,20),
// replicate-padded at front, unbiased std, sd clamped at 1e-4.
//
// R5 design: NO LDS. The 20-step history lives in REGISTERS as a static
// shift-ring: time loop unrolled in groups of 20 so all ring indices are
// compile-time constants. Two 20-reg arrays (A, Bv) swap IN/HIST roles per
// group; next group's loads are issued into HIST[g] right after its last
// use (step g) -> 20-deep per-wave software pipeline, ~1 group (~1.7k cy)
// of load lead time. Removes the per-step ds_read->lgkmcnt->ds_write chain
// that R3/R4 stalled on, and the 40KB LDS occupancy tax.
// Block = 256 threads (one per column, H split in 2), grid 32 x 2 x 32.
// __launch_bounds__(256,8) targets <=64 VGPR -> 32 waves/CU.

#define BB 32
#define TT 2048
#define HH 512
#define HB 256      // columns per block
#define CHUNK 64    // t-rows per block: 20+20+20+4 groups

__constant__ constexpr float INV_W_[3]   = {0.2f, 0.1f, 0.05f};
__constant__ constexpr float INV_WM1_[3] = {0.25f, 1.0f/9.0f, 1.0f/19.0f};

static __device__ __forceinline__ float step_compute(float v, float o5, float o10, float o20,
                                                     float (&S)[3], float (&S2)[3],
                                                     const float (&aw)[3]) {
    const float od[3] = {o5, o10, o20};
    const float vv = v * v;
    float acc = 0.f;
    #pragma unroll
    for (int i = 0; i < 3; ++i) {
        S[i]  += v - od[i];
        S2[i] += fmaf(-od[i], od[i], vv);                       // += v*v - oo*oo
        const float mu  = S[i] * INV_W_[i];
        const float var = fmaxf(fmaf(-S[i], mu, S2[i]) * INV_WM1_[i], 0.f);
        const float rs  = fminf(__builtin_amdgcn_rsqf(var), 1e4f);
        acc = fmaf((v - mu) * rs, aw[i], acc);
    }
    return acc;
}

// One group of NSTEP (<=20) t-steps starting at row `base`.
// IN[g]  = x[base+g]   (loaded by the previous group)
// HIST[k]= x[base-20+k]
// Issues NLOAD loads for the NEXT group into HIST[g] (rows base+20+g),
// each right after HIST[g]'s last read (o20 at step g). All indices static.
template<int NSTEP, int NLOAD>
static __device__ __forceinline__ void run_group(const float* __restrict__ px,
                                                 float* __restrict__ po, int base,
                                                 float (&IN)[20], float (&HIST)[20],
                                                 float (&S)[3], float (&S2)[3],
                                                 const float (&aw)[3]) {
    #pragma unroll
    for (int g = 0; g < NSTEP; ++g) {
        const float v   = IN[g];
        const float o20 = HIST[g];
        const float o5  = (g >= 5)  ? IN[g - 5]  : HIST[g + 15];
        const float o10 = (g >= 10) ? IN[g - 10] : HIST[g + 10];
        const float acc = step_compute(v, o5, o10, o20, S, S2, aw);
        __builtin_nontemporal_store(acc, po + (size_t)(base + g) * HH);
        if (g < NLOAD) HIST[g] = px[(size_t)(base + 20 + g) * HH];
    }
}

__global__ __launch_bounds__(256, 8) void fan_kernel(const float* __restrict__ x,
                                                     const float* __restrict__ alpha,
                                                     float* __restrict__ out) {
    const int tid = threadIdx.x;
    const int t0  = blockIdx.x * CHUNK;
    const int h   = blockIdx.y * HB + tid;   // feature column
    const int b   = blockIdx.z;

    // per-feature softmax over the 3 windows
    float aw[3];
    {
        const float* a = alpha + 3 * h;
        float f0 = a[0], f1 = a[1], f2 = a[2];
        float mx = fmaxf(f0, fmaxf(f1, f2));
        float e0 = __expf(f0 - mx);
        float e1 = __expf(f1 - mx);
        float e2 = __expf(f2 - mx);
        float inv = 1.0f / (e0 + e1 + e2);
        aw[0] = e0 * inv; aw[1] = e1 * inv; aw[2] = e2 * inv;
    }

    const float* __restrict__ px = x   + (size_t)b * TT * HH + h;
    float*       __restrict__ po = out + (size_t)b * TT * HH + h;

    float S[3]  = {0.f, 0.f, 0.f};
    float S2[3] = {0.f, 0.f, 0.f};
    float A[20], Bv[20];   // register shift-ring, role-swapped per group

    if (t0 == 0) {
        constexpr int W_[3] = {5, 10, 20};
        // ---- pass 1: prescan rows [0,20) into A, prefix checkpoints at 5,10,15,20
        float P = 0.f, Q = 0.f;
        float CP[4], CQ[4];
        #pragma unroll
        for (int t = 0; t < 20; ++t) {
            float v = px[(size_t)t * HH];
            A[t] = v;
            P += v; Q += v * v;
            if (t == 4 || t == 9 || t == 14 || t == 19) {
                const int ci = (t + 1) / 5 - 1;
                CP[ci] = P; CQ[ci] = Q;
            }
        }
        // replicate stats: windows [0,w-1] -> checkpoints 5,10,20 (idx 0,1,3)
        float rmu[3], rrsd[3];
        constexpr int CMAP[3] = {0, 1, 3};
        #pragma unroll
        for (int i = 0; i < 3; ++i) {
            float s = CP[CMAP[i]], s2 = CQ[CMAP[i]];
            float mu  = s * INV_W_[i];
            float var = fmaxf((s2 - s * mu) * INV_WM1_[i], 0.f);
            rmu[i]  = mu;
            rrsd[i] = fminf(__builtin_amdgcn_rsqf(var), 1e4f);
        }
        // issue first main-group loads (rows 20..39) -> hidden under pass 2
        #pragma unroll
        for (int g = 0; g < 20; ++g) Bv[g] = px[(size_t)(20 + g) * HH];
        // ---- pass 2: outputs [0,20) from register ring, running clipped sums
        #pragma unroll
        for (int t = 0; t < 20; ++t) {
            float v = A[t];
            float acc = 0.f;
            #pragma unroll
            for (int i = 0; i < 3; ++i) {
                if (t >= W_[i]) {
                    float o = A[t - W_[i]];
                    S[i]  += v - o;
                    S2[i] += v * v - o * o;
                } else {
                    S[i]  += v;
                    S2[i] += v * v;
                }
                float mu, rs;
                if (t >= W_[i] - 1) {
                    mu = S[i] * INV_W_[i];
                    float var = fmaxf((S2[i] - S[i] * mu) * INV_WM1_[i], 0.f);
                    rs = fminf(__builtin_amdgcn_rsqf(var), 1e4f);
                } else {
                    mu = rmu[i]; rs = rrsd[i];
                }
                acc = fmaf((v - mu) * rs, aw[i], acc);
            }
            __builtin_nontemporal_store(acc, &po[(size_t)t * HH]);
        }
        // entry sums for t=20: S_w = P20 - P(20-w)
        S[0] = CP[3] - CP[2];  S2[0] = CQ[3] - CQ[2];
        S[1] = CP[3] - CP[1];  S2[1] = CQ[3] - CQ[1];
        S[2] = CP[3];          S2[2] = CQ[3];

        // main: rows [20,64). A = rows 0..19, Bv = rows 20..39 (in flight)
        run_group<20, 20>(px, po, 20, Bv, A,  S, S2, aw);  // loads A  <- 40..59
        run_group<20,  4>(px, po, 40, A,  Bv, S, S2, aw);  // loads Bv[0..3] <- 60..63
        run_group< 4,  0>(px, po, 60, Bv, A,  S, S2, aw);
    } else {
        // ---- interior warm-up: rows [t0-20, t0) -> A + clipped sums
        #pragma unroll
        for (int k = 0; k < 20; ++k) {
            float v = px[(size_t)(t0 - 20 + k) * HH];
            A[k] = v;
            if (k >= 15) { S[0] += v; S2[0] += v * v; }   // last 5
            if (k >= 10) { S[1] += v; S2[1] += v * v; }   // last 10
            {             S[2] += v; S2[2] += v * v; }    // last 20
        }
        // issue first main-group loads (rows t0..t0+19)
        #pragma unroll
        for (int g = 0; g < 20; ++g) Bv[g] = px[(size_t)(t0 + g) * HH];

        run_group<20, 20>(px, po, t0,      Bv, A,  S, S2, aw);  // loads A  <- t0+20..39
        run_group<20, 20>(px, po, t0 + 20, A,  Bv, S, S2, aw);  // loads Bv <- t0+40..59
        run_group<20,  4>(px, po, t0 + 40, Bv, A,  S, S2, aw);  // loads A[0..3] <- t0+60..63
        run_group< 4,  0>(px, po, t0 + 60, A,  Bv, S, S2, aw);
    }
}

extern "C" void kernel_launch(void* const* d_in, const int* in_sizes, int n_in,
                              void* d_out, int out_size, void* d_ws, size_t ws_size,
                              hipStream_t stream) {
    const float* x     = (const float*)d_in[0];
    const float* alpha = (const float*)d_in[1];
    float*       out   = (float*)d_out;

    dim3 grid(TT / CHUNK, HH / HB, BB);   // 32 x 2 x 32 = 2048 blocks
    dim3 block(HB);                        // one thread per feature column
    fan_kernel<<<grid, block, 0, stream>>>(x, alpha, out);
}

// Round 3
// 244.102 us; speedup vs baseline: 1.0142x; 1.0075x over previous
//
#include <hip/hip_runtime.h>
#include <math.h>

// x: [B=32, T=2048, H=512] fp32, alpha: [H,3] -> out [B,T,H] fp32.
// Per-feature softmax blend of 3 sliding-window z-scores (w=5,10,20),
// replicate-padded at front, unbiased std, sd clamped at 1e-4.
//
// R6 design: register shift-ring, float2 per thread, NO LDS.
// R5 post-mortem: __launch_bounds__(256,8) (64-VGPR cap) made the allocator
// SPILL the 20-deep ring to scratch (VGPR_Count=32, WRITE_SIZE +7MB). Fix:
//  - __launch_bounds__(256,4) -> 128-VGPR cap, ring actually fits in regs.
//  - float2 per thread: packed fp32 VALU (v_pk_*) halves per-element issue,
//    dwordx2 loads/stores halve per-byte instruction count.
// Time loop unrolled in groups of 20 so all ring indices are compile-time;
// two v2f[20] arrays swap IN/HIST roles per group; next group's load issued
// into HIST[g] right after its last use (step g) -> ~1 group of lead time.

typedef float v2f __attribute__((ext_vector_type(2)));

#define BB 32
#define TT 2048
#define HH 512
#define H2 256      // float2 columns
#define CHUNK 64    // t-rows per block: groups 20+20+20+4

__constant__ constexpr float INV_W_[3]   = {0.2f, 0.1f, 0.05f};
__constant__ constexpr float INV_WM1_[3] = {0.25f, 1.0f/9.0f, 1.0f/19.0f};

static __device__ __forceinline__ v2f vmax2(v2f a, v2f b) { return __builtin_elementwise_max(a, b); }
static __device__ __forceinline__ v2f vmin2(v2f a, v2f b) { return __builtin_elementwise_min(a, b); }
static __device__ __forceinline__ v2f vrsq2(v2f a) {
    v2f r; r.x = __builtin_amdgcn_rsqf(a.x); r.y = __builtin_amdgcn_rsqf(a.y); return r;
}

static __device__ __forceinline__ v2f step_compute(v2f v, v2f o5, v2f o10, v2f o20,
                                                   v2f (&S)[3], v2f (&S2)[3],
                                                   const v2f (&aw)[3]) {
    const v2f od[3] = {o5, o10, o20};
    const v2f vv = v * v;
    v2f acc = {0.f, 0.f};
    #pragma unroll
    for (int i = 0; i < 3; ++i) {
        S[i]  += v - od[i];
        S2[i] += vv - od[i] * od[i];
        const v2f mu  = S[i] * INV_W_[i];
        const v2f var = vmax2((S2[i] - S[i] * mu) * INV_WM1_[i], v2f{0.f, 0.f});
        const v2f rs  = vmin2(vrsq2(var), v2f{1e4f, 1e4f});
        acc += (v - mu) * rs * aw[i];
    }
    return acc;
}

// One group of NSTEP (<=20) t-steps starting at row `base`.
// IN[g] = x[base+g] (loaded by previous group); HIST[k] = x[base-20+k].
// Issues NLOAD loads for the NEXT group into HIST[g] (rows base+20+g),
// each right after HIST[g]'s last read (o20 at step g). All indices static.
template<int NSTEP, int NLOAD>
static __device__ __forceinline__ void run_group(const v2f* __restrict__ px,
                                                 v2f* __restrict__ po, int base,
                                                 v2f (&IN)[20], v2f (&HIST)[20],
                                                 v2f (&S)[3], v2f (&S2)[3],
                                                 const v2f (&aw)[3]) {
    #pragma unroll
    for (int g = 0; g < NSTEP; ++g) {
        const v2f v   = IN[g];
        const v2f o20 = HIST[g];
        const v2f o5  = (g >= 5)  ? IN[g - 5]  : HIST[g + 15];
        const v2f o10 = (g >= 10) ? IN[g - 10] : HIST[g + 10];
        const v2f acc = step_compute(v, o5, o10, o20, S, S2, aw);
        __builtin_nontemporal_store(acc, po + (size_t)(base + g) * H2);
        if (g < NLOAD) HIST[g] = px[(size_t)(base + 20 + g) * H2];
    }
}

__global__ __launch_bounds__(256, 4) void fan_kernel(const float* __restrict__ x,
                                                     const float* __restrict__ alpha,
                                                     float* __restrict__ out) {
    const int tid = threadIdx.x;              // float2 column index
    const int t0  = blockIdx.x * CHUNK;
    const int b   = blockIdx.y;

    // per-feature softmax over the 3 windows (2 channels per thread)
    v2f aw[3];
    {
        const v2f* a2 = (const v2f*)alpha + 3 * tid;   // 6 contiguous floats
        v2f A0 = a2[0], A1 = a2[1], A2 = a2[2];
        float f[2][3] = {{A0.x, A0.y, A1.x}, {A1.y, A2.x, A2.y}};
        float w[2][3];
        #pragma unroll
        for (int j = 0; j < 2; ++j) {
            float mx = fmaxf(f[j][0], fmaxf(f[j][1], f[j][2]));
            float e0 = __expf(f[j][0] - mx);
            float e1 = __expf(f[j][1] - mx);
            float e2 = __expf(f[j][2] - mx);
            float inv = 1.0f / (e0 + e1 + e2);
            w[j][0] = e0 * inv; w[j][1] = e1 * inv; w[j][2] = e2 * inv;
        }
        #pragma unroll
        for (int i = 0; i < 3; ++i) { aw[i].x = w[0][i]; aw[i].y = w[1][i]; }
    }

    const v2f* __restrict__ px = (const v2f*)x + (size_t)b * TT * H2 + tid;
    v2f*       __restrict__ po = (v2f*)out     + (size_t)b * TT * H2 + tid;

    v2f S[3]  = {{0,0},{0,0},{0,0}};
    v2f S2[3] = {{0,0},{0,0},{0,0}};
    v2f A[20], Bv[20];   // register shift-ring, role-swapped per group

    if (t0 == 0) {
        constexpr int W_[3] = {5, 10, 20};
        // ---- pass 1: prescan rows [0,20) into A, prefix checkpoints at 5,10,15,20
        v2f P = {0,0}, Q = {0,0};
        v2f CP[4], CQ[4];
        #pragma unroll
        for (int t = 0; t < 20; ++t) {
            v2f v = px[(size_t)t * H2];
            A[t] = v;
            P += v; Q += v * v;
            if (t == 4 || t == 9 || t == 14 || t == 19) {
                const int ci = (t + 1) / 5 - 1;
                CP[ci] = P; CQ[ci] = Q;
            }
        }
        // replicate stats: windows [0,w-1] -> checkpoints 5,10,20 (idx 0,1,3)
        v2f rmu[3], rrsd[3];
        constexpr int CMAP[3] = {0, 1, 3};
        #pragma unroll
        for (int i = 0; i < 3; ++i) {
            v2f s = CP[CMAP[i]], s2 = CQ[CMAP[i]];
            v2f mu  = s * INV_W_[i];
            v2f var = vmax2((s2 - s * mu) * INV_WM1_[i], v2f{0.f, 0.f});
            rmu[i]  = mu;
            rrsd[i] = vmin2(vrsq2(var), v2f{1e4f, 1e4f});
        }
        // issue first main-group loads (rows 20..39) -> hidden under pass 2
        #pragma unroll
        for (int g = 0; g < 20; ++g) Bv[g] = px[(size_t)(20 + g) * H2];
        // ---- pass 2: outputs [0,20) from register ring, running clipped sums
        #pragma unroll
        for (int t = 0; t < 20; ++t) {
            v2f v = A[t];
            v2f acc = {0.f, 0.f};
            #pragma unroll
            for (int i = 0; i < 3; ++i) {
                if (t >= W_[i]) {
                    v2f o = A[t - W_[i]];
                    S[i]  += v - o;
                    S2[i] += v * v - o * o;
                } else {
                    S[i]  += v;
                    S2[i] += v * v;
                }
                v2f mu, rs;
                if (t >= W_[i] - 1) {
                    mu = S[i] * INV_W_[i];
                    v2f var = vmax2((S2[i] - S[i] * mu) * INV_WM1_[i], v2f{0.f, 0.f});
                    rs = vmin2(vrsq2(var), v2f{1e4f, 1e4f});
                } else {
                    mu = rmu[i]; rs = rrsd[i];
                }
                acc += (v - mu) * rs * aw[i];
            }
            __builtin_nontemporal_store(acc, &po[(size_t)t * H2]);
        }
        // entry sums for t=20: S_w = P20 - P(20-w)
        S[0] = CP[3] - CP[2];  S2[0] = CQ[3] - CQ[2];
        S[1] = CP[3] - CP[1];  S2[1] = CQ[3] - CQ[1];
        S[2] = CP[3];          S2[2] = CQ[3];

        // main: rows [20,64). A = rows 0..19, Bv = rows 20..39 (in flight)
        run_group<20, 20>(px, po, 20, Bv, A,  S, S2, aw);  // loads A  <- 40..59
        run_group<20,  4>(px, po, 40, A,  Bv, S, S2, aw);  // loads Bv[0..3] <- 60..63
        run_group< 4,  0>(px, po, 60, Bv, A,  S, S2, aw);
    } else {
        // ---- interior warm-up: rows [t0-20, t0) -> A + clipped sums
        #pragma unroll
        for (int k = 0; k < 20; ++k) {
            v2f v = px[(size_t)(t0 - 20 + k) * H2];
            A[k] = v;
            if (k >= 15) { S[0] += v; S2[0] += v * v; }   // last 5
            if (k >= 10) { S[1] += v; S2[1] += v * v; }   // last 10
            {             S[2] += v; S2[2] += v * v; }    // last 20
        }
        // issue first main-group loads (rows t0..t0+19)
        #pragma unroll
        for (int g = 0; g < 20; ++g) Bv[g] = px[(size_t)(t0 + g) * H2];

        run_group<20, 20>(px, po, t0,      Bv, A,  S, S2, aw);  // loads A  <- t0+20..39
        run_group<20, 20>(px, po, t0 + 20, A,  Bv, S, S2, aw);  // loads Bv <- t0+40..59
        run_group<20,  4>(px, po, t0 + 40, Bv, A,  S, S2, aw);  // loads A[0..3] <- t0+60..63
        run_group< 4,  0>(px, po, t0 + 60, A,  Bv, S, S2, aw);
    }
}

extern "C" void kernel_launch(void* const* d_in, const int* in_sizes, int n_in,
                              void* d_out, int out_size, void* d_ws, size_t ws_size,
                              hipStream_t stream) {
    const float* x     = (const float*)d_in[0];
    const float* alpha = (const float*)d_in[1];
    float*       out   = (float*)d_out;

    dim3 grid(TT / CHUNK, BB);   // 32 x 32 = 1024 blocks
    dim3 block(H2);              // one thread per float2 column
    fan_kernel<<<grid, block, 0, stream>>>(x, alpha, out);
}